// Round 6
// baseline (359.767 us; speedup 1.0000x reference)
//
#include <hip/hip_runtime.h>
#include <math.h>

// ---------------------------------------------------------------------------
// Problem: B=4, L=4096, D=P=256, tau=0.5
// out = (1/8) * sum_{b,l} [ log(S1-e^2) + log(S2-e^2) - 4*d[b,l] ]
//   S[b,q] = sum_{m<2L} exp(2 * Zhat[b,q].Zhat[b,m]),  Zhat = [z1n; z2n]
//   d[b,l] = z1n[b,l].z2n[b,l]
// Flash-gram R6: NO LDS, NO barriers in the hot loop.  Both A and B frags of
// 16x16x32 NT-MFMA are 16 contiguous bytes of a zn row, so B streams straight
// global->VGPR with a 4-slot rotating prefetch (3 steps ahead).  Waves run
// fully independent; wm-paired waves on one SIMD share B addresses (L1 hits).
// ---------------------------------------------------------------------------

typedef __attribute__((ext_vector_type(8))) short short8;
typedef __attribute__((ext_vector_type(4))) short short4v;
typedef __attribute__((ext_vector_type(4))) float float4v;

__device__ __forceinline__ short f2bf(float f) {
    unsigned u = __builtin_bit_cast(unsigned, f);
    u += 0x7fffu + ((u >> 16) & 1u);          // RNE
    return (short)(u >> 16);
}

__device__ __forceinline__ void gl_lds16(const short* g, short* l) {
    __builtin_amdgcn_global_load_lds(
        (const __attribute__((address_space(1))) void*)g,
        (__attribute__((address_space(3))) void*)l, 16, 0, 0);
}

// ---------------------------------------------------------------------------
// 512-thread NT-GEMM core (verified R2/R3): C[RAxRB] = A*B^T, K=256.
// ---------------------------------------------------------------------------
template <int RA, int RB, int NWM>
__device__ __forceinline__ void gemm512_core(
    const short* __restrict__ A, const short* __restrict__ B,
    int arow0, int brow0, short* lsA, short* lsB, float4v acc[4][4])
{
    const int tid  = threadIdx.x;
    const int w    = tid >> 6;
    const int lane = tid & 63;
    const int wm   = w % NWM;
    const int wn   = w / NWM;
    constexpr int ACH = RA / 8;

    for (int kt = 0; kt < 4; ++kt) {
        const int kbase = kt * 64;
#pragma unroll
        for (int r = 0; r < 6; ++r) {
            const int c = w * 6 + r;
            if (c < ACH) {
                const int s   = c * 64 + lane;
                const int kc  = s / RA;
                const int row = s % RA;
                gl_lds16(A + (size_t)(arow0 + row) * 256 + kbase + kc * 8,
                         lsA + (size_t)c * 512);
            } else {
                const int s   = (c - ACH) * 64 + lane;
                const int kc  = s / RB;
                const int row = s % RB;
                gl_lds16(B + (size_t)(brow0 + row) * 256 + kbase + kc * 8,
                         lsB + (size_t)(c - ACH) * 512);
            }
        }
        __syncthreads();
#pragma unroll
        for (int ks = 0; ks < 2; ++ks) {
            const int kc = ks * 4 + (lane >> 4);
            short8 af[4], bfv[4];
#pragma unroll
            for (int mi = 0; mi < 4; ++mi)
                af[mi] = *(const short8*)(lsA + ((size_t)kc * RA + wm * 64 + mi * 16 + (lane & 15)) * 8);
#pragma unroll
            for (int ni = 0; ni < 4; ++ni)
                bfv[ni] = *(const short8*)(lsB + ((size_t)kc * RB + wn * 64 + ni * 16 + (lane & 15)) * 8);
#pragma unroll
            for (int mi = 0; mi < 4; ++mi)
#pragma unroll
                for (int ni = 0; ni < 4; ++ni)
                    acc[mi][ni] = __builtin_amdgcn_mfma_f32_16x16x32_bf16(
                        af[mi], bfv[ni], acc[mi][ni], 0, 0, 0);
        }
        __syncthreads();
    }
}

// ---------------------------------------------------------------------------
// fp32 -> bf16 converters
// ---------------------------------------------------------------------------
__global__ __launch_bounds__(256) void convX_kernel(
    const float* __restrict__ X1, const float* __restrict__ X2,
    short* __restrict__ dst)
{
    int i = blockIdx.x * 256 + threadIdx.x;
    const float* src = (i < 1048576) ? X1 : X2;
    int j = i & 1048575;
    float4v v = ((const float4v*)src)[j];
    short4v o;
    o.x = f2bf(v.x); o.y = f2bf(v.y); o.z = f2bf(v.z); o.w = f2bf(v.w);
    ((short4v*)dst)[i] = o;
}

__global__ __launch_bounds__(256) void convW_kernel(
    const float* __restrict__ W1, const float* __restrict__ W2,
    short* __restrict__ d1, short* __restrict__ d2)
{
    int i = blockIdx.x * 256 + threadIdx.x;
    const float* src = (i < 16384) ? W1 : W2;
    short* dst = (i < 16384) ? d1 : d2;
    int j = i & 16383;
    float4v v = ((const float4v*)src)[j];
    short4v o;
    o.x = f2bf(v.x); o.y = f2bf(v.y); o.z = f2bf(v.z); o.w = f2bf(v.w);
    ((short4v*)dst)[j] = o;
}

// ---------------------------------------------------------------------------
// proj1: H = elu(X*W1^T + b1) bf16, 32768x256, grid 256 x 512thr.
// ---------------------------------------------------------------------------
__global__ __launch_bounds__(512) void proj1_kernel(
    const short* __restrict__ Xbf, const short* __restrict__ W1bf,
    const float* __restrict__ b1, short* __restrict__ Hbf)
{
    __shared__ short lsA[8192];
    __shared__ short lsB[16384];
    const int arow0 = blockIdx.x * 128;
    float4v acc[4][4];
#pragma unroll
    for (int mi = 0; mi < 4; ++mi)
#pragma unroll
        for (int ni = 0; ni < 4; ++ni)
            acc[mi][ni] = (float4v){0.f, 0.f, 0.f, 0.f};

    gemm512_core<128, 256, 2>(Xbf, W1bf, arow0, 0, lsA, lsB, acc);

    const int tid  = threadIdx.x;
    const int w    = tid >> 6;
    const int lane = tid & 63;
    const int wm   = w % 2;
    const int wn   = w / 2;
    const int rowbase = arow0 + wm * 64 + (lane >> 4) * 4;
    const int colbase = wn * 64 + (lane & 15);
#pragma unroll
    for (int ni = 0; ni < 4; ++ni) {
        const int col = colbase + ni * 16;
        const float bv = b1[col];
#pragma unroll
        for (int mi = 0; mi < 4; ++mi)
#pragma unroll
            for (int reg = 0; reg < 4; ++reg) {
                const int row = rowbase + mi * 16 + reg;
                float v = acc[mi][ni][reg] + bv;
                v = (v > 0.f) ? v : expm1f(v);
                Hbf[(size_t)row * 256 + col] = f2bf(v);
            }
    }
}

// ---------------------------------------------------------------------------
// proj2 + normalize fused -> zn bf16 in [b][set][l][256] order.
// ---------------------------------------------------------------------------
__global__ __launch_bounds__(512) void proj2norm_kernel(
    const short* __restrict__ Hbf, const short* __restrict__ W2bf,
    const float* __restrict__ b2, short* __restrict__ zn)
{
    __shared__ short lsA[8192];
    __shared__ short lsB[16384];
    __shared__ float rssq[4][128];
    __shared__ float rinv[128];
    const int arow0 = blockIdx.x * 128;
    float4v acc[4][4];
#pragma unroll
    for (int mi = 0; mi < 4; ++mi)
#pragma unroll
        for (int ni = 0; ni < 4; ++ni)
            acc[mi][ni] = (float4v){0.f, 0.f, 0.f, 0.f};

    gemm512_core<128, 256, 2>(Hbf, W2bf, arow0, 0, lsA, lsB, acc);

    const int tid  = threadIdx.x;
    const int w    = tid >> 6;
    const int lane = tid & 63;
    const int wm   = w % 2;
    const int wn   = w / 2;

#pragma unroll
    for (int ni = 0; ni < 4; ++ni) {
        const float bv = b2[wn * 64 + ni * 16 + (lane & 15)];
#pragma unroll
        for (int mi = 0; mi < 4; ++mi)
#pragma unroll
            for (int reg = 0; reg < 4; ++reg)
                acc[mi][ni][reg] += bv;
    }
    float ps[4][4];
#pragma unroll
    for (int mi = 0; mi < 4; ++mi)
#pragma unroll
        for (int reg = 0; reg < 4; ++reg) {
            float s = 0.f;
#pragma unroll
            for (int ni = 0; ni < 4; ++ni) {
                float v = acc[mi][ni][reg];
                s += v * v;
            }
            s += __shfl_xor(s, 1); s += __shfl_xor(s, 2);
            s += __shfl_xor(s, 4); s += __shfl_xor(s, 8);
            ps[mi][reg] = s;
        }
    if ((lane & 15) == 0) {
        const int g = lane >> 4;
#pragma unroll
        for (int mi = 0; mi < 4; ++mi)
#pragma unroll
            for (int reg = 0; reg < 4; ++reg)
                rssq[wn][wm * 64 + mi * 16 + g * 4 + reg] = ps[mi][reg];
    }
    __syncthreads();
    if (tid < 128) {
        float ssq = rssq[0][tid] + rssq[1][tid] + rssq[2][tid] + rssq[3][tid];
        rinv[tid] = 1.0f / fmaxf(sqrtf(ssq), 1e-12f);
    }
    __syncthreads();

    const int r0  = arow0;
    const int set = r0 >> 14;
    const int bb  = (r0 >> 12) & 3;
    const int l0  = r0 & 4095;
    short* dst = zn + ((size_t)(bb * 2 + set) * 4096 + l0) * 256;
    const int colbase = wn * 64 + (lane & 15);
#pragma unroll
    for (int mi = 0; mi < 4; ++mi)
#pragma unroll
        for (int reg = 0; reg < 4; ++reg) {
            const int rl = wm * 64 + mi * 16 + (lane >> 4) * 4 + reg;
            const float inv = rinv[rl];
#pragma unroll
            for (int ni = 0; ni < 4; ++ni)
                dst[(size_t)rl * 256 + colbase + ni * 16] =
                    f2bf(acc[mi][ni][reg] * inv);
        }
}

// ---------------------------------------------------------------------------
// Flash-gram R6: grid 256 blocks x 512 threads, wave = 64 rows x 32 cols
// (wave grid 2 wm x 4 wn).  A-stripe frags in regs (once).  B frags stream
// global->VGPR with 4-slot rotating prefetch, 3 k-steps ahead; slot indices
// are compile-time after the kc unroll (8j mod 4 == 0).  No LDS / barriers
// in the loop.  Epilogue (verified R5): combine wn-partials in LDS before
// log; diag of cross tile gives -2*dsum over both orientations = -4d.
// NOTE: prefetch at j=63 overreads into tile 64 (lands in Hbf region of the
// workspace -- in-bounds, never consumed).
// ---------------------------------------------------------------------------
__global__ __launch_bounds__(512, 2) void gram_flash_kernel(
    const short* __restrict__ zn, float* __restrict__ out)
{
    __shared__ float smS[4][128];     // [wn][row] rowsum partials
    __shared__ float redl[8];         // per-wave log-sums
    __shared__ float redd[8];         // per-wave dsum

    const int bx     = blockIdx.x;            // 0..255
    const int xcd    = bx & 7;                // batch -> XCD pair {2b,2b+1}
    const int batch  = xcd >> 1;
    const int stripe = (bx >> 3) * 2 + (xcd & 1);   // 0..63
    const short* Z = zn + (size_t)batch * (8192 * 256);
    const int q0 = stripe * 128;
    const int dj = (stripe < 32) ? (stripe + 32) : (stripe - 32);

    const int tid  = threadIdx.x;
    const int w    = tid >> 6;
    const int lane = tid & 63;
    const int wm   = w & 1;        // m-half (64 rows)
    const int wn   = w >> 1;       // n-quarter (32 cols)
    const int quad = lane >> 4;
    const int l15  = lane & 15;

    // ---- A fragments global->regs (once).  A[m=l15][k=quad*8+j]
    short8 afr[4][8];
    {
        const short* Ab = Z + (size_t)(q0 + wm * 64) * 256;
#pragma unroll
        for (int mi = 0; mi < 4; ++mi)
#pragma unroll
            for (int kc = 0; kc < 8; ++kc)
                afr[mi][kc] = *(const short8*)(Ab + (size_t)(mi * 16 + l15) * 256
                                               + kc * 32 + quad * 8);
    }

    // ---- B streaming pointers: frag(ni,kc,tile) = 16B at
    //   Z + (tile*128 + wn*32 + ni*16 + l15)*256 + kc*32 + quad*8
    const short* Bp0 = Z + (size_t)(wn * 32 + l15) * 256 + quad * 8;
    const short* Bp1 = Bp0 + 16 * 256;

    short8 bb[4][2];                  // rotating, slot = step & 3
#pragma unroll
    for (int p = 0; p < 3; ++p) {     // preload steps 0,1,2 (tile 0, kc 0..2)
        bb[p][0] = *(const short8*)(Bp0 + p * 32);
        bb[p][1] = *(const short8*)(Bp1 + p * 32);
    }

    float rs[4][4];
#pragma unroll
    for (int mi = 0; mi < 4; ++mi)
#pragma unroll
        for (int reg = 0; reg < 4; ++reg)
            rs[mi][reg] = 0.f;
    float dsum = 0.f;

    for (int j = 0; j < 64; ++j) {
        float4v acc[4][2];
#pragma unroll
        for (int mi = 0; mi < 4; ++mi) {
            acc[mi][0] = (float4v){0.f, 0.f, 0.f, 0.f};
            acc[mi][1] = (float4v){0.f, 0.f, 0.f, 0.f};
        }
        const size_t jb = (size_t)j * 32768;
#pragma unroll
        for (int kc = 0; kc < 8; ++kc) {
            // prefetch step 8j+kc+3 into slot (kc+3)&3 (compile-time)
            const int   slot = (kc + 3) & 3;
            const size_t off = jb + (size_t)((kc + 3) >> 3) * 32768
                                  + (size_t)((kc + 3) & 7) * 32;
            bb[slot][0] = *(const short8*)(Bp0 + off);
            bb[slot][1] = *(const short8*)(Bp1 + off);
            // compute with slot kc&3
            const int cs = kc & 3;
#pragma unroll
            for (int mi = 0; mi < 4; ++mi) {
                acc[mi][0] = __builtin_amdgcn_mfma_f32_16x16x32_bf16(
                    afr[mi][kc], bb[cs][0], acc[mi][0], 0, 0, 0);
                acc[mi][1] = __builtin_amdgcn_mfma_f32_16x16x32_bf16(
                    afr[mi][kc], bb[cs][1], acc[mi][1], 0, 0, 0);
            }
        }

        if (j == dj) {   // raw z1.z2 diagonal of the cross tile
#pragma unroll
            for (int mi = 0; mi < 4; ++mi)
#pragma unroll
                for (int ni = 0; ni < 2; ++ni)
#pragma unroll
                    for (int reg = 0; reg < 4; ++reg) {
                        const int row = wm * 64 + mi * 16 + quad * 4 + reg;
                        const int col = wn * 32 + ni * 16 + l15;
                        if (row == col) dsum += acc[mi][ni][reg];
                    }
        }

#pragma unroll
        for (int mi = 0; mi < 4; ++mi)
#pragma unroll
            for (int reg = 0; reg < 4; ++reg)
                rs[mi][reg] += __expf(2.0f * acc[mi][0][reg])
                             + __expf(2.0f * acc[mi][1][reg]);
    }

    // ---- epilogue: combine the 4 wn-wave 32-col partials per row in LDS,
    // THEN log(S - e2) (log is nonlinear -- R4 lesson).
    const float E2 = 7.3890560989306495f;   // exp(1/tau) = e^2
#pragma unroll
    for (int mi = 0; mi < 4; ++mi)
#pragma unroll
        for (int reg = 0; reg < 4; ++reg) {
            float v = rs[mi][reg];
            v += __shfl_xor(v, 1); v += __shfl_xor(v, 2);
            v += __shfl_xor(v, 4); v += __shfl_xor(v, 8);
            rs[mi][reg] = v;
        }
    if (l15 == 0) {
#pragma unroll
        for (int mi = 0; mi < 4; ++mi)
#pragma unroll
            for (int reg = 0; reg < 4; ++reg)
                smS[wn][wm * 64 + mi * 16 + quad * 4 + reg] = rs[mi][reg];
    }
    {
        float dv = dsum;
        dv += __shfl_xor(dv, 1);  dv += __shfl_xor(dv, 2);
        dv += __shfl_xor(dv, 4);  dv += __shfl_xor(dv, 8);
        dv += __shfl_xor(dv, 16); dv += __shfl_xor(dv, 32);
        if (lane == 0) redd[w] = dv;
    }
    __syncthreads();

    float local = 0.f;
    if (tid < 128)
        local = logf(smS[0][tid] + smS[1][tid] + smS[2][tid] + smS[3][tid] - E2);
    local += __shfl_xor(local, 1);  local += __shfl_xor(local, 2);
    local += __shfl_xor(local, 4);  local += __shfl_xor(local, 8);
    local += __shfl_xor(local, 16); local += __shfl_xor(local, 32);
    if (lane == 0) redl[w] = local;
    __syncthreads();
    if (tid == 0) {
        float t = redl[0] + redl[1] + redl[2] + redl[3]
                + redl[4] + redl[5] + redl[6] + redl[7]
                - 2.0f * (redd[0] + redd[1] + redd[2] + redd[3]
                        + redd[4] + redd[5] + redd[6] + redd[7]);
        atomicAdd(out, 0.125f * t);
    }
}

// ---------------------------------------------------------------------------
// Workspace (bytes), total ~33.8 MB:
//   [0,       131072)  W1bf
//   [131072,  262144)  W2bf
//   [262144,17039360)  Xbf / zn (aliased; Xbf dead after proj1)
//   [17039360,33816576) Hbf  (also absorbs gram's tile-64 prefetch overread)
// ---------------------------------------------------------------------------
extern "C" void kernel_launch(void* const* d_in, const int* in_sizes, int n_in,
                              void* d_out, int out_size, void* d_ws, size_t ws_size,
                              hipStream_t stream)
{
    const float* X1 = (const float*)d_in[0];
    const float* X2 = (const float*)d_in[1];
    const float* W1 = (const float*)d_in[2];
    const float* b1 = (const float*)d_in[3];
    const float* W2 = (const float*)d_in[4];
    const float* b2 = (const float*)d_in[5];

    char* ws = (char*)d_ws;
    short* W1bf = (short*)(ws + 0);
    short* W2bf = (short*)(ws + 131072);
    short* Xbf  = (short*)(ws + 262144);
    short* zn   = (short*)(ws + 262144);
    short* Hbf  = (short*)(ws + 17039360);

    hipMemsetAsync(d_out, 0, sizeof(float), stream);

    convW_kernel<<<128, 256, 0, stream>>>(W1, W2, W1bf, W2bf);
    convX_kernel<<<8192, 256, 0, stream>>>(X1, X2, Xbf);
    proj1_kernel<<<256, 512, 0, stream>>>(Xbf, W1bf, b1, Hbf);
    proj2norm_kernel<<<256, 512, 0, stream>>>(Hbf, W2bf, b2, zn);
    gram_flash_kernel<<<256, 512, 0, stream>>>(zn, (float*)d_out);
}